// Round 8
// baseline (139.849 us; speedup 1.0000x reference)
//
#include <hip/hip_runtime.h>
#include <hip/hip_bf16.h>
#include <stdint.h>

// Problem constants
#define Bb  2
#define Ss  2048
#define Hh  768
#define NHh 12
#define HDd 64

typedef short bf16x8 __attribute__((ext_vector_type(8)));
typedef float f32x4  __attribute__((ext_vector_type(4)));
typedef unsigned short u16x4 __attribute__((ext_vector_type(4)));

// f32 -> bf16 round-to-nearest-even
__device__ __forceinline__ unsigned short f2bf(float x) {
    union { float f; unsigned int u; } v; v.f = x;
    unsigned int r = v.u + 0x7fffu + ((v.u >> 16) & 1u);
    return (unsigned short)(r >> 16);
}

// async global->LDS, 16B per lane (dest must be wave-uniform base + lane*16)
__device__ __forceinline__ void gl_lds16(const unsigned short* g, unsigned short* l) {
    __builtin_amdgcn_global_load_lds(
        (const __attribute__((address_space(1))) unsigned int*)g,
        (__attribute__((address_space(3))) unsigned int*)l, 16, 0, 0);
}

// ---------------------------------------------------------------------------
// Cast hs [4096x768], Wq [768x768], Wk [768x768] f32 -> bf16.  (R2 verbatim)
// ---------------------------------------------------------------------------
__global__ __launch_bounds__(256)
void cast_kernel(const float* __restrict__ hs, const float* __restrict__ Wq,
                 const float* __restrict__ Wk,
                 unsigned short* __restrict__ hsb, unsigned short* __restrict__ Wqb,
                 unsigned short* __restrict__ Wkb)
{
    int cid = blockIdx.x * 256 + threadIdx.x;      // 0 .. 540671
    const float* src; unsigned short* dst; int base;
    if (cid < 393216)      { src = hs; dst = hsb; base = cid; }
    else if (cid < 466944) { src = Wq; dst = Wqb; base = cid - 393216; }
    else                   { src = Wk; dst = Wkb; base = cid - 466944; }
    float4 a0 = ((const float4*)src)[(size_t)base * 2];
    float4 a1 = ((const float4*)src)[(size_t)base * 2 + 1];
    bf16x8 v;
    v[0] = (short)f2bf(a0.x); v[1] = (short)f2bf(a0.y);
    v[2] = (short)f2bf(a0.z); v[3] = (short)f2bf(a0.w);
    v[4] = (short)f2bf(a1.x); v[5] = (short)f2bf(a1.y);
    v[6] = (short)f2bf(a1.z); v[7] = (short)f2bf(a1.w);
    ((bf16x8*)dst)[base] = v;
}

// ---------------------------------------------------------------------------
// Projection (R2 verbatim): Out[m,n] = sum_k hsb[m,k]*Wb[n,k] + bias[n].
// 128x128 tile, BK=64, 4 waves, swapped operands -> ushort4 stores.
// ---------------------------------------------------------------------------
__global__ __launch_bounds__(256)
void proj_kernel(const unsigned short* __restrict__ hsb,
                 const unsigned short* __restrict__ Wqb,
                 const unsigned short* __restrict__ Wkb,
                 const float* __restrict__ bq, const float* __restrict__ bk,
                 unsigned short* __restrict__ Qb, unsigned short* __restrict__ Kb)
{
    const int zq = blockIdx.z;
    const unsigned short* __restrict__ Wb = zq ? Wkb : Wqb;
    const float* __restrict__ bias = zq ? bk : bq;
    unsigned short* __restrict__ Out = zq ? Kb : Qb;

    const int m0 = blockIdx.x * 128;
    const int n0 = blockIdx.y * 128;

    __shared__ unsigned short As[128 * 64];
    __shared__ unsigned short Bs[128 * 64];

    const int tid  = threadIdx.x;
    const int lane = tid & 63;
    const int w    = tid >> 6;
    const int wm   = (w >> 1) * 64;
    const int wn   = (w & 1) * 64;
    const int lg   = lane >> 4;
    const int l15  = lane & 15;

    f32x4 acc[4][4] = {};

    for (int k0 = 0; k0 < Hh; k0 += 64) {
        #pragma unroll
        for (int i = 0; i < 4; ++i) {
            int cc  = i * 256 + tid;
            int row = cc >> 3, seg = (cc & 7) * 8;
            gl_lds16(hsb + (size_t)(m0 + row) * Hh + k0 + seg, &As[cc * 8]);
            gl_lds16(Wb  + (size_t)(n0 + row) * Hh + k0 + seg, &Bs[cc * 8]);
        }
        __syncthreads();

        #pragma unroll
        for (int kk = 0; kk < 2; ++kk) {
            const int kof = kk * 32 + lg * 8;
            bf16x8 wf[4], hf[4];
            #pragma unroll
            for (int i = 0; i < 4; ++i)
                wf[i] = *(bf16x8*)&Bs[(wm + i * 16 + l15) * 64 + kof];
            #pragma unroll
            for (int j = 0; j < 4; ++j)
                hf[j] = *(bf16x8*)&As[(wn + j * 16 + l15) * 64 + kof];
            #pragma unroll
            for (int i = 0; i < 4; ++i)
                #pragma unroll
                for (int j = 0; j < 4; ++j)
                    acc[i][j] = __builtin_amdgcn_mfma_f32_16x16x32_bf16(
                        wf[i], hf[j], acc[i][j], 0, 0, 0);
        }
        __syncthreads();
    }

    #pragma unroll
    for (int i = 0; i < 4; ++i) {
        const int nb = n0 + wm + i * 16 + lg * 4;
        const float4 bv = *(const float4*)&bias[nb];
        #pragma unroll
        for (int j = 0; j < 4; ++j) {
            const int m = m0 + wn + j * 16 + l15;
            u16x4 o;
            o[0] = f2bf(acc[i][j][0] + bv.x);
            o[1] = f2bf(acc[i][j][1] + bv.y);
            o[2] = f2bf(acc[i][j][2] + bv.z);
            o[3] = f2bf(acc[i][j][3] + bv.w);
            *(u16x4*)&Out[(size_t)m * Hh + nb] = o;
        }
    }
}

// ---------------------------------------------------------------------------
// Scores v3: wave-decoupled full-k streaming.
// Block = (b, h, 64-row q-strip); 768 blocks = 3.0/CU. Wave owns 16 q rows,
// streams all 2048 K rows in 32 chunks (64 rows x 64 d) through a
// WAVE-PRIVATE LDS double buffer. No __syncthreads anywhere: pipelining by
// in-order vmcnt counting (8 load_lds + 4 stores per iter -> vmcnt(12)
// guarantees previous chunk's loads retired, stores never drained).
// Each (q,h) out row gets its full 8KB written by one wave in order ->
// DRAM row-buffer friendly. Q frags loaded once from global to regs.
// ---------------------------------------------------------------------------
__global__ __launch_bounds__(256)
void score_kernel(const unsigned short* __restrict__ Qb,
                  const unsigned short* __restrict__ Kb,
                  const float* __restrict__ mask,
                  float* __restrict__ out)
{
    const int bid = blockIdx.x;                    // 0..767
    const int bh  = bid >> 5;                      // 0..23
    const int qt  = bid & 31;                      // q-strip
    const int b   = bh / NHh, h = bh % NHh;

    __shared__ unsigned short Ks[4][2][4096];      // per-wave dbuf, 64KB total

    const int tid  = threadIdx.x;
    const int lane = tid & 63;
    const int w    = tid >> 6;
    const int lg   = lane >> 4;
    const int l15  = lane & 15;
    const int q    = qt * 64 + w * 16 + l15;       // this lane's q row

    // Q fragments: one row, 16B-contiguous at h*64 + kof. Loaded once.
    const unsigned short* qrow = Qb + (size_t)(b * Ss + q) * Hh + h * HDd;
    const bf16x8 qf0 = *(const bf16x8*)&qrow[lg * 8];
    const bf16x8 qf1 = *(const bf16x8*)&qrow[32 + lg * 8];
    const float  mv  = mask[b * Ss + q];
    float* orow = out + ((size_t)(b * Ss + q) * NHh + h) * Ss;

    const unsigned short* kbase = Kb + (size_t)b * Ss * Hh + h * HDd;
    unsigned short* myk = &Ks[w][0][0];

    // ---- prologue: stage chunks 0 (buf0) and 1 (buf1) ----
    #pragma unroll
    for (int i = 0; i < 8; ++i) {
        int cc = i * 64 + lane, row = cc >> 3, seg = cc & 7;
        gl_lds16(kbase + (size_t)row * Hh + ((seg ^ (row & 7)) << 3), myk + cc * 8);
    }
    #pragma unroll
    for (int i = 0; i < 8; ++i) {
        int cc = i * 64 + lane, row = cc >> 3, seg = cc & 7;
        gl_lds16(kbase + (size_t)(64 + row) * Hh + ((seg ^ (row & 7)) << 3),
                 myk + 4096 + cc * 8);
    }
    asm volatile("s_waitcnt vmcnt(8)" ::: "memory");   // chunk 0 resident
    __builtin_amdgcn_sched_barrier(0);

    // ---- compute chunk 0 ----
    {
        const unsigned short* src = myk;
        #pragma unroll
        for (int m = 0; m < 4; ++m) {
            const int row = m * 16 + l15;
            bf16x8 k0 = *(const bf16x8*)&src[(row << 6) + ((lg ^ (l15 & 7)) << 3)];
            bf16x8 k1 = *(const bf16x8*)&src[(row << 6) + (((4 + lg) ^ (l15 & 7)) << 3)];
            f32x4 acc = {};
            acc = __builtin_amdgcn_mfma_f32_16x16x32_bf16(k0, qf0, acc, 0, 0, 0);
            acc = __builtin_amdgcn_mfma_f32_16x16x32_bf16(k1, qf1, acc, 0, 0, 0);
            f32x4 o;
            float v0 = acc[0] * 0.125f + mv;
            float v1 = acc[1] * 0.125f + mv;
            float v2 = acc[2] * 0.125f + mv;
            float v3 = acc[3] * 0.125f + mv;
            o[0] = v0 > 0.f ? v0 : 0.f;
            o[1] = v1 > 0.f ? v1 : 0.f;
            o[2] = v2 > 0.f ? v2 : 0.f;
            o[3] = v3 > 0.f ? v3 : 0.f;
            *(f32x4*)&orow[m * 16 + lg * 4] = o;
        }
    }

    // ---- steady state ----
    for (int ct = 1; ct < 32; ++ct) {
        const int buf = ct & 1;
        const int nct = (ct + 1) & 31;             // wrap: last iter restages 0
        unsigned short* dst = myk + (buf ^ 1) * 4096;
        #pragma unroll
        for (int i = 0; i < 8; ++i) {
            int cc = i * 64 + lane, row = cc >> 3, seg = cc & 7;
            gl_lds16(kbase + (size_t)(nct * 64 + row) * Hh + ((seg ^ (row & 7)) << 3),
                     dst + cc * 8);
        }
        // newest 12 = 4 stores(ct-1) + 8 loads(ct+1); retires loads(ct).
        asm volatile("s_waitcnt vmcnt(12)" ::: "memory");
        __builtin_amdgcn_sched_barrier(0);

        const unsigned short* src = myk + buf * 4096;
        #pragma unroll
        for (int m = 0; m < 4; ++m) {
            const int row = m * 16 + l15;
            bf16x8 k0 = *(const bf16x8*)&src[(row << 6) + ((lg ^ (l15 & 7)) << 3)];
            bf16x8 k1 = *(const bf16x8*)&src[(row << 6) + (((4 + lg) ^ (l15 & 7)) << 3)];
            f32x4 acc = {};
            acc = __builtin_amdgcn_mfma_f32_16x16x32_bf16(k0, qf0, acc, 0, 0, 0);
            acc = __builtin_amdgcn_mfma_f32_16x16x32_bf16(k1, qf1, acc, 0, 0, 0);
            f32x4 o;
            float v0 = acc[0] * 0.125f + mv;
            float v1 = acc[1] * 0.125f + mv;
            float v2 = acc[2] * 0.125f + mv;
            float v3 = acc[3] * 0.125f + mv;
            o[0] = v0 > 0.f ? v0 : 0.f;
            o[1] = v1 > 0.f ? v1 : 0.f;
            o[2] = v2 > 0.f ? v2 : 0.f;
            o[3] = v3 > 0.f ? v3 : 0.f;
            *(f32x4*)&orow[ct * 64 + m * 16 + lg * 4] = o;
        }
    }
}

// ---------------------------------------------------------------------------
extern "C" void kernel_launch(void* const* d_in, const int* in_sizes, int n_in,
                              void* d_out, int out_size, void* d_ws, size_t ws_size,
                              hipStream_t stream) {
    const float* hs   = (const float*)d_in[0];
    const float* mask = (const float*)d_in[1];
    // d_in[2] = input_ids (unused), d_in[3] = ngram (unused)
    const float* Wq = (const float*)d_in[4];
    const float* bq = (const float*)d_in[5];
    const float* Wk = (const float*)d_in[6];
    const float* bk = (const float*)d_in[7];
    float* out = (float*)d_out;

    // Workspace layout (bf16 elements):
    unsigned short* Qb  = (unsigned short*)d_ws;   // 4096*768
    unsigned short* Kb  = Qb  + 3145728;
    unsigned short* hsb = Kb  + 3145728;
    unsigned short* Wqb = hsb + 3145728;           // 768*768
    unsigned short* Wkb = Wqb + 589824;

    cast_kernel<<<2112, 256, 0, stream>>>(hs, Wq, Wk, hsb, Wqb, Wkb);
    proj_kernel<<<dim3(32, 6, 2), 256, 0, stream>>>(hsb, Wqb, Wkb, bq, bk, Qb, Kb);
    score_kernel<<<768, 256, 0, stream>>>(Qb, Kb, mask, out);
}

// Round 9
// 125.028 us; speedup vs baseline: 1.1185x; 1.1185x over previous
//
#include <hip/hip_runtime.h>
#include <hip/hip_bf16.h>
#include <stdint.h>

// Problem constants
#define Bb  2
#define Ss  2048
#define Hh  768
#define NHh 12
#define HDd 64

typedef short bf16x8 __attribute__((ext_vector_type(8)));
typedef float f32x4  __attribute__((ext_vector_type(4)));
typedef unsigned short u16x4 __attribute__((ext_vector_type(4)));

// f32 -> bf16 round-to-nearest-even
__device__ __forceinline__ unsigned short f2bf(float x) {
    union { float f; unsigned int u; } v; v.f = x;
    unsigned int r = v.u + 0x7fffu + ((v.u >> 16) & 1u);
    return (unsigned short)(r >> 16);
}

// async global->LDS, 16B per lane (dest must be wave-uniform base + lane*16)
__device__ __forceinline__ void gl_lds16(const unsigned short* g, unsigned short* l) {
    __builtin_amdgcn_global_load_lds(
        (const __attribute__((address_space(1))) unsigned int*)g,
        (__attribute__((address_space(3))) unsigned int*)l, 16, 0, 0);
}

// ---------------------------------------------------------------------------
// Projection with fused f32->bf16 staging (no separate cast kernel):
// Out[m,n] = sum_k hs[m,k]*W[n,k] + bias[n], bf16 out.
// 128x128 tile, BK=64, 4 waves. Staging loads f32, converts to bf16 in
// registers, ds_writes b128 (R1-proven). MFMA/epilogue identical to R2:
// swapped operands -> acc reg axis = output cols -> ushort4 8B stores.
// ---------------------------------------------------------------------------
__global__ __launch_bounds__(256)
void proj_kernel(const float* __restrict__ hs,
                 const float* __restrict__ Wq, const float* __restrict__ Wk,
                 const float* __restrict__ bq, const float* __restrict__ bk,
                 unsigned short* __restrict__ Qb, unsigned short* __restrict__ Kb)
{
    const int zq = blockIdx.z;
    const float* __restrict__ W    = zq ? Wk : Wq;
    const float* __restrict__ bias = zq ? bk : bq;
    unsigned short* __restrict__ Out = zq ? Kb : Qb;

    const int m0 = blockIdx.x * 128;               // hs-row tile (output rows)
    const int n0 = blockIdx.y * 128;               // W-row tile (output cols)

    __shared__ unsigned short As[128 * 64];        // hs rows  [row][k] bf16
    __shared__ unsigned short Bs[128 * 64];        // W rows   [row][k] bf16

    const int tid  = threadIdx.x;
    const int lane = tid & 63;
    const int w    = tid >> 6;
    const int wm   = (w >> 1) * 64;                // W-side sub-tile (out cols)
    const int wn   = (w & 1) * 64;                 // hs-side sub-tile (out rows)
    const int lg   = lane >> 4;
    const int l15  = lane & 15;

    f32x4 acc[4][4] = {};

    for (int k0 = 0; k0 < Hh; k0 += 64) {
        // ---- stage + convert: 8 f32 -> 8 bf16 per thread per buffer ----
        #pragma unroll
        for (int i = 0; i < 4; ++i) {
            int cc  = i * 256 + tid;               // 8-elem chunk id
            int row = cc >> 3, seg = (cc & 7) * 8;
            const float* ga = hs + (size_t)(m0 + row) * Hh + k0 + seg;
            const float* gb = W  + (size_t)(n0 + row) * Hh + k0 + seg;
            float4 a0 = *(const float4*)ga, a1 = *(const float4*)(ga + 4);
            float4 b0 = *(const float4*)gb, b1 = *(const float4*)(gb + 4);
            bf16x8 va, vb;
            va[0] = (short)f2bf(a0.x); va[1] = (short)f2bf(a0.y);
            va[2] = (short)f2bf(a0.z); va[3] = (short)f2bf(a0.w);
            va[4] = (short)f2bf(a1.x); va[5] = (short)f2bf(a1.y);
            va[6] = (short)f2bf(a1.z); va[7] = (short)f2bf(a1.w);
            vb[0] = (short)f2bf(b0.x); vb[1] = (short)f2bf(b0.y);
            vb[2] = (short)f2bf(b0.z); vb[3] = (short)f2bf(b0.w);
            vb[4] = (short)f2bf(b1.x); vb[5] = (short)f2bf(b1.y);
            vb[6] = (short)f2bf(b1.z); vb[7] = (short)f2bf(b1.w);
            *(bf16x8*)&As[row * 64 + seg] = va;
            *(bf16x8*)&Bs[row * 64 + seg] = vb;
        }
        __syncthreads();

        #pragma unroll
        for (int kk = 0; kk < 2; ++kk) {
            const int kof = kk * 32 + lg * 8;
            bf16x8 wf[4], hf[4];
            #pragma unroll
            for (int i = 0; i < 4; ++i)
                wf[i] = *(bf16x8*)&Bs[(wm + i * 16 + l15) * 64 + kof];
            #pragma unroll
            for (int j = 0; j < 4; ++j)
                hf[j] = *(bf16x8*)&As[(wn + j * 16 + l15) * 64 + kof];
            #pragma unroll
            for (int i = 0; i < 4; ++i)
                #pragma unroll
                for (int j = 0; j < 4; ++j)
                    acc[i][j] = __builtin_amdgcn_mfma_f32_16x16x32_bf16(
                        wf[i], hf[j], acc[i][j], 0, 0, 0);
        }
        __syncthreads();
    }

    // Epilogue: reg axis = 4 consecutive output columns -> ushort4 store.
    #pragma unroll
    for (int i = 0; i < 4; ++i) {
        const int nb = n0 + wm + i * 16 + lg * 4;
        const float4 bv = *(const float4*)&bias[nb];
        #pragma unroll
        for (int j = 0; j < 4; ++j) {
            const int m = m0 + wn + j * 16 + l15;
            u16x4 o;
            o[0] = f2bf(acc[i][j][0] + bv.x);
            o[1] = f2bf(acc[i][j][1] + bv.y);
            o[2] = f2bf(acc[i][j][2] + bv.z);
            o[3] = f2bf(acc[i][j][3] + bv.w);
            *(u16x4*)&Out[(size_t)m * Hh + nb] = o;
        }
    }
}

// ---------------------------------------------------------------------------
// Scores (R2 VERBATIM): out[b,q,h,k] = relu( (Q_h[q,:].K_h[k,:])/8 + mask[b,q] )
// 128x128 tile per (b,h), gl_lds16 staging, swapped operands -> f32x4 stores.
// ---------------------------------------------------------------------------
__global__ __launch_bounds__(256)
void score_kernel(const unsigned short* __restrict__ Qb,
                  const unsigned short* __restrict__ Kb,
                  const float* __restrict__ mask,
                  float* __restrict__ out)
{
    const int q0 = blockIdx.x * 128;
    const int c0 = blockIdx.y * 128;               // key-tile origin
    const int bh = blockIdx.z;
    const int b  = bh / NHh, h = bh % NHh;

    __shared__ unsigned short Qs[128 * 64];
    __shared__ unsigned short Ks[128 * 64];

    const int tid  = threadIdx.x;
    const int lane = tid & 63;
    const int w    = tid >> 6;
    const int wm   = (w >> 1) * 64;                // K-side (out cols)
    const int wn   = (w & 1) * 64;                 // Q-side (out rows)
    const int lg   = lane >> 4;
    const int l15  = lane & 15;

    #pragma unroll
    for (int i = 0; i < 4; ++i) {
        int cc  = i * 256 + tid;
        int row = cc >> 3, seg = (cc & 7) * 8;
        gl_lds16(Qb + (size_t)(b * Ss + q0 + row) * Hh + h * HDd + seg, &Qs[cc * 8]);
        gl_lds16(Kb + (size_t)(b * Ss + c0 + row) * Hh + h * HDd + seg, &Ks[cc * 8]);
    }
    __syncthreads();

    f32x4 acc[4][4] = {};
    #pragma unroll
    for (int kk = 0; kk < 2; ++kk) {
        const int kof = kk * 32 + lg * 8;
        bf16x8 kf[4], qf[4];
        #pragma unroll
        for (int m = 0; m < 4; ++m)
            kf[m] = *(bf16x8*)&Ks[(wm + m * 16 + l15) * 64 + kof];
        #pragma unroll
        for (int n = 0; n < 4; ++n)
            qf[n] = *(bf16x8*)&Qs[(wn + n * 16 + l15) * 64 + kof];
        #pragma unroll
        for (int m = 0; m < 4; ++m)
            #pragma unroll
            for (int n = 0; n < 4; ++n)
                acc[m][n] = __builtin_amdgcn_mfma_f32_16x16x32_bf16(
                    kf[m], qf[n], acc[m][n], 0, 0, 0);
    }

    // Epilogue: per (n) the query row q; per (m) 4 consecutive k -> 16B store.
    #pragma unroll
    for (int n = 0; n < 4; ++n) {
        const int q = q0 + wn + n * 16 + l15;
        const float mv = mask[b * Ss + q];
        float* orow = out + ((size_t)(b * Ss + q) * NHh + h) * Ss;
        #pragma unroll
        for (int m = 0; m < 4; ++m) {
            const int kb = c0 + wm + m * 16 + lg * 4;
            f32x4 o;
            float v0 = acc[m][n][0] * 0.125f + mv;
            float v1 = acc[m][n][1] * 0.125f + mv;
            float v2 = acc[m][n][2] * 0.125f + mv;
            float v3 = acc[m][n][3] * 0.125f + mv;
            o[0] = v0 > 0.f ? v0 : 0.f;
            o[1] = v1 > 0.f ? v1 : 0.f;
            o[2] = v2 > 0.f ? v2 : 0.f;
            o[3] = v3 > 0.f ? v3 : 0.f;
            *(f32x4*)&orow[kb] = o;
        }
    }
}

// ---------------------------------------------------------------------------
extern "C" void kernel_launch(void* const* d_in, const int* in_sizes, int n_in,
                              void* d_out, int out_size, void* d_ws, size_t ws_size,
                              hipStream_t stream) {
    const float* hs   = (const float*)d_in[0];
    const float* mask = (const float*)d_in[1];
    // d_in[2] = input_ids (unused), d_in[3] = ngram (unused)
    const float* Wq = (const float*)d_in[4];
    const float* bq = (const float*)d_in[5];
    const float* Wk = (const float*)d_in[6];
    const float* bk = (const float*)d_in[7];
    float* out = (float*)d_out;

    // Workspace layout (bf16 elements): only Q and K now.
    unsigned short* Qb = (unsigned short*)d_ws;    // 4096*768
    unsigned short* Kb = Qb + 3145728;

    proj_kernel<<<dim3(32, 6, 2), 256, 0, stream>>>(hs, Wq, Wk, bq, bk, Qb, Kb);
    score_kernel<<<dim3(16, 16, 24), 256, 0, stream>>>(Qb, Kb, mask, out);
}